// Round 16
// baseline (148.869 us; speedup 1.0000x reference)
//
#include <hip/hip_runtime.h>
#include <hip/hip_fp16.h>
#include <math.h>

#define B_    8
#define C_    64
#define N_    4096
#define OUT_  64
#define KNN_  20
#define KP_   28     // candidates kept per row for f64 rerank (slack for bf16 Gram + u16 quant)

// single-pass selection params
#define CAPL_ 176            // per-query main list capacity (lambda ~77, >10 sigma)
#define LSTR_ 177            // list stride (bank-stagger)
#define CAP2_ 64             // compacted list capacity (~36 expected)
#define L2S_  65             // list2/bhist stride (bank-stagger)
#define QSCK_ 546.13333f     // 65536 / 120  (score range [-80, 40) -> u16)
#define KQ_   (-2.0f * QSCK_)
#define KC_   (80.0f * QSCK_)

typedef __attribute__((ext_vector_type(8)))  short bf16x8;
typedef __attribute__((ext_vector_type(16))) float f32x16;

__device__ __forceinline__ unsigned short bf16rtn(float f) {
    unsigned u = __float_as_uint(f);
    u += 0x7FFFu + ((u >> 16) & 1u);
    return (unsigned short)(u >> 16);
}

__device__ __forceinline__ unsigned packf16(float a, float b) {
    __half ha = __float2half(a), hb = __float2half(b);
    unsigned short ua = *(unsigned short*)&ha, ub = *(unsigned short*)&hb;
    return (unsigned)ua | ((unsigned)ub << 16);
}

// ---------------------------------------------------------------------------
// Kernel 1: fused prep. Per block: 64-point tile of one batch.
// ---------------------------------------------------------------------------
__global__ __launch_bounds__(256) void k_prep(const float* __restrict__ x,
                                              const float* __restrict__ W,
                                              const float* __restrict__ bias,
                                              float* __restrict__ u,
                                              float* __restrict__ v,
                                              float* __restrict__ sq32,
                                              double* __restrict__ sq64,
                                              uint4* __restrict__ xh,
                                              float* __restrict__ xT,
                                              float2* __restrict__ sqp) {
    __shared__ float xs[64][65];     // [c][n]
    __shared__ float Wd[64 * 64];    // [c][o] = W1 - W2
    __shared__ float W2s[64 * 64];   // [c][o] = W2
    const int tid = threadIdx.x;
    const int b = blockIdx.x >> 6, nb = (blockIdx.x & 63) << 6;

    for (int k = 0; k < 16; ++k) {
        int i = tid + k * 256;
        int o = i & 63, c = i >> 6;
        float w1 = W[o * 128 + c];
        float w2 = W[o * 128 + 64 + c];
        Wd[c * 64 + o]  = w1 - w2;
        W2s[c * 64 + o] = w2;
    }
    for (int k = 0; k < 16; ++k) {
        int i = tid + k * 256;
        int c = i >> 6, n = i & 63;
        xs[c][n] = x[((size_t)b * 64 + c) * N_ + nb + n];
    }
    __syncthreads();

    const int o = tid & 63, w = tid >> 6;
    float uacc[16], vacc[16];
    #pragma unroll
    for (int i = 0; i < 16; ++i) { uacc[i] = 0.f; vacc[i] = 0.f; }
    for (int c = 0; c < 64; ++c) {
        float wd = Wd[c * 64 + o], w2 = W2s[c * 64 + o];
        #pragma unroll
        for (int i = 0; i < 16; ++i) {
            float xc = xs[c][w * 16 + i];
            uacc[i] = fmaf(wd, xc, uacc[i]);
            vacc[i] = fmaf(w2, xc, vacc[i]);
        }
    }
    const float bo = bias[o];
    #pragma unroll
    for (int i = 0; i < 16; ++i) {
        size_t row = (size_t)b * N_ + nb + w * 16 + i;
        u[row * 64 + o] = uacc[i] + bo;
        v[row * 64 + o] = vacc[i];
    }

    {   // pack xh (hi bf16 only)
        const int nl = tid & 63;
        #pragma unroll
        for (int gg = 0; gg < 2; ++gg) {
            const int g = (tid >> 6) + gg * 4;
            unsigned hw[4];
            #pragma unroll
            for (int e = 0; e < 4; ++e) {
                float x0 = xs[g * 8 + 2 * e][nl];
                float x1 = xs[g * 8 + 2 * e + 1][nl];
                hw[e] = (unsigned)bf16rtn(x0) | ((unsigned)bf16rtn(x1) << 16);
            }
            xh[(size_t)(b * 8 + g) * N_ + nb + nl] = make_uint4(hw[0], hw[1], hw[2], hw[3]);
        }
    }

    if (xT) {
        for (int k = 0; k < 16; ++k) {
            int i = tid + k * 256;
            int n = i >> 6, c = i & 63;
            xT[((size_t)b * N_ + nb + n) * 64 + c] = xs[c][n];
        }
    }

    // squared norms (f64 exact) + per-block stats partial (wave 0 only)
    if (tid < 64) {
        const int n = tid;
        double sq = 0.0;
        for (int c = 0; c < 64; ++c) {
            double xd = (double)xs[c][n];
            sq = fma(xd, xd, sq);
        }
        sq64[(size_t)b * N_ + nb + n] = sq;
        float fs = (float)sq;
        sq32[(size_t)b * N_ + nb + n] = fs;
        float s1 = fs, s2 = fs * fs;
        #pragma unroll
        for (int d = 1; d < 64; d <<= 1) {
            s1 += __shfl_xor(s1, d);
            s2 += __shfl_xor(s2, d);
        }
        if (tid == 0) sqp[blockIdx.x] = make_float2(s1, s2);
    }
}

// ---------------------------------------------------------------------------
// Kernel 2: SINGLE-PASS MFMA Gram + analytic-gate selection.
// 32 queries/block x 1024 blocks, 8 waves; XCD swizzle batch = blockIdx & 7.
// R14 structure; TIGHTENED gate (z=-2.12, lambda~77) + float-med3 clamp in
// the accept body; short rows (P~2e-4) padded with -1 sentinels (k_rrs maps
// them to d2=+inf, so selection stays exact).
// ---------------------------------------------------------------------------
__global__ __launch_bounds__(512, 8) void k_knn(const uint4* __restrict__ xh,
                                                const float* __restrict__ sq32,
                                                const float2* __restrict__ sqp,
                                                int* __restrict__ idx24) {
    extern __shared__ char smem[];
    unsigned* list  = (unsigned*)smem;                  // 32*177*4 = 22656
    unsigned* bhist = (unsigned*)(smem + 22656);        // 32*65*4  = 8320
    unsigned* list2 = (unsigned*)(smem + 30976);        // 32*65*4  = 8320
    unsigned* cnt   = (unsigned*)(smem + 39296);        // 128
    unsigned* cnt2  = (unsigned*)(smem + 39424);        // 128
    unsigned* edge  = (unsigned*)(smem + 39552);        // 128  -> total 39680

    const int tid = threadIdx.x;
    const int b   = blockIdx.x & 7;                 // XCD-affinity swizzle
    const int qb  = (blockIdx.x >> 3) << 5;         // q-group of 32
    const int wid = tid >> 6, l = tid & 63, h = l >> 5, ql = l & 31;
    const int jq  = wid * 512;
    const uint4* xhb = xh + (size_t)b * 8 * N_;
    const float* sqb = sq32 + b * N_;

    for (int i = tid; i < 32 * L2S_; i += 512) bhist[i] = 0u;
    if (tid < 32) { cnt[tid] = 0u; cnt2[tid] = 0u; }

    // batch stats from 64 k_prep partials (redundant per-wave reduce)
    float2 pp = sqp[b * 64 + l];
    float s1 = pp.x, s2 = pp.y;
    #pragma unroll
    for (int d = 1; d < 64; d <<= 1) { s1 += __shfl_xor(s1, d); s2 += __shfl_xor(s2, d); }
    const float mean = s1 * (1.0f / 4096.f);
    const float var  = s2 * (1.0f / 4096.f) - mean * mean;

    // per-lane gate: tightened z (lambda ~77; P(true-20 miss) ~4e-11/query)
    const float sqi = sqb[qb + ql];
    const float gg = -0.5f * (mean + 0.75f - 2.12f * sqrtf(var + 4.f * sqi));

    // B fragments (queries), persistent in regs
    bf16x8 Bh[4];
    #pragma unroll
    for (int kk = 0; kk < 4; ++kk)
        Bh[kk] = *(const bf16x8*)&xhb[(size_t)(2 * kk + h) * N_ + qb + ql];
    __syncthreads();   // lists/counts zeroed

    const int qq = ql;
    #pragma unroll 1
    for (int t = 0; t < 16; ++t) {
        const int jb = jq + t * 32;
        bf16x8 Ah[4];
        #pragma unroll
        for (int kk = 0; kk < 4; ++kk)
            Ah[kk] = *(const bf16x8*)&xhb[(size_t)(2 * kk + h) * N_ + jb + ql];
        float4 q0 = *(const float4*)(sqb + jb + 4 * h);
        float4 q1 = *(const float4*)(sqb + jb + 8 + 4 * h);
        float4 q2 = *(const float4*)(sqb + jb + 16 + 4 * h);
        float4 q3 = *(const float4*)(sqb + jb + 24 + 4 * h);

        float sq16[16];
        sq16[0]=q0.x; sq16[1]=q0.y; sq16[2]=q0.z; sq16[3]=q0.w;
        sq16[4]=q1.x; sq16[5]=q1.y; sq16[6]=q1.z; sq16[7]=q1.w;
        sq16[8]=q2.x; sq16[9]=q2.y; sq16[10]=q2.z; sq16[11]=q2.w;
        sq16[12]=q3.x; sq16[13]=q3.y; sq16[14]=q3.z; sq16[15]=q3.w;

        // fold -0.5*sq_j into the accumulator init: final a = dot - 0.5 sq_j
        f32x16 a0;
        #pragma unroll
        for (int i = 0; i < 16; ++i) a0[i] = -0.5f * sq16[i];
        #pragma unroll
        for (int kk = 0; kk < 4; ++kk)
            a0 = __builtin_amdgcn_mfma_f32_32x32x16_bf16(Ah[kk], Bh[kk], a0, 0, 0, 0);

        const int jv0 = jb + 4 * h;
        #pragma unroll
        for (int r = 0; r < 16; ++r) {
            float av = a0[r];
            if (av > gg) {
                float qf = fmaf(av, KQ_, KC_);               // quantized score
                qf = fminf(fmaxf(qf, 0.0f), 65535.0f);       // v_med3_f32
                unsigned key = ((unsigned)(int)qf << 12) |
                               (unsigned)(jv0 + (r & 3) + 8 * (r >> 2));
                unsigned slot = atomicAdd(&cnt[qq], 1u);
                if (slot < CAPL_) list[qq * LSTR_ + slot] = key;
            }
        }
    }
    __syncthreads();                    // all appends done

    // clamp counts, then build the bucket histogram from the stored keys
    if (tid < 32) {
        unsigned cc = cnt[tid];
        cnt[tid] = cc > CAPL_ ? CAPL_ : cc;
    }
    __syncthreads();
    {
        const int qh = tid >> 4, ph = tid & 15;
        const int cnh = (int)cnt[qh];
        for (int e = ph; e < cnh; e += 16)
            atomicAdd(&bhist[qh * L2S_ + (list[qh * LSTR_ + e] >> 22)], 1u);
    }
    __syncthreads();                    // histogram complete

    if (tid < 32) {
        unsigned c = 0, E = 63;
        #pragma unroll 1
        for (int bin = 0; bin < 64; ++bin) {
            c += bhist[tid * L2S_ + bin];
            if (c >= KP_) { E = (unsigned)bin; break; }
        }
        edge[tid] = E;
    }
    __syncthreads();

    const int qq2 = tid >> 4, pt = tid & 15;
    {   // compact: keep bucket <= E (~36 expected)
        const unsigned E = edge[qq2];
        const int cn = (int)cnt[qq2];
        for (int e = pt; e < cn; e += 16) {
            unsigned key = list[qq2 * LSTR_ + e];
            if ((key >> 22) <= E) {
                unsigned s2i = atomicAdd(&cnt2[qq2], 1u);
                if (s2i < CAP2_) list2[qq2 * L2S_ + s2i] = key;
            }
        }
    }
    __syncthreads();
    {   // exact rank-select top-28 by u32 key; pad short rows with -1 sentinel
        int cn2 = (int)cnt2[qq2]; cn2 = cn2 > CAP2_ ? CAP2_ : cn2;
        const size_t row = (size_t)b * N_ + qb + qq2;
        for (int e = pt; e < cn2; e += 16) {
            unsigned key = list2[qq2 * L2S_ + e];
            int rk = 0;
            for (int o = 0; o < cn2; ++o) rk += (list2[qq2 * L2S_ + o] < key);
            if (rk < KP_) idx24[row * KP_ + rk] = (int)(key & 0xFFFu);
        }
        for (int e = cn2 + pt; e < KP_; e += 16)
            idx24[row * KP_ + e] = -1;
    }
}

// ---------------------------------------------------------------------------
// Kernel 3 (fast, fused): f64 re-rank (xT) + BN stats + packed (max,min)
// in place into u.  Sentinel (-1) candidates rank last (d2 = 1e300).
// ---------------------------------------------------------------------------
__global__ __launch_bounds__(256) void k_rrs(const float* __restrict__ xT,
                                             const double* __restrict__ sq64,
                                             const int* __restrict__ idx24,
                                             int* __restrict__ idx20,
                                             float* u,
                                             const float* __restrict__ v,
                                             float* __restrict__ psum,
                                             float* __restrict__ psq) {
    __shared__ float qs[8][64];
    __shared__ int   ii20[8][KNN_];
    __shared__ float red[512];
    const int tid = threadIdx.x;
    const int rl = tid >> 5, lane = tid & 31;
    const int bb = blockIdx.x & 7;                  // XCD-affinity swizzle
    const int rowBase = bb * N_ + (blockIdx.x >> 3) * 8;
    #pragma unroll
    for (int i = 0; i < 2; ++i) {
        int idx = tid + i * 256;
        qs[idx >> 6][idx & 63] = xT[(size_t)(rowBase + (idx >> 6)) * 64 + (idx & 63)];
    }
    __syncthreads();
    const int row = rowBase + rl;
    const int b = bb;
    const int craw = (lane < KP_) ? idx24[(size_t)row * KP_ + lane] : -1;
    const bool cvalid = craw >= 0;
    const int cand = cvalid ? (craw & (N_ - 1)) : 0;
    const float* __restrict__ cp = xT + ((size_t)b * N_ + cand) * 64;
    double d0 = 0.0, d1 = 0.0, d2p = 0.0, d3 = 0.0;   // 4-way split chain
    #pragma unroll
    for (int c4 = 0; c4 < 16; ++c4) {
        float4 p4 = *(const float4*)(cp + c4 * 4);
        float4 q4 = *(const float4*)(&qs[rl][c4 * 4]);
        d0 = fma((double)q4.x, (double)p4.x, d0);
        d1 = fma((double)q4.y, (double)p4.y, d1);
        d2p = fma((double)q4.z, (double)p4.z, d2p);
        d3 = fma((double)q4.w, (double)p4.w, d3);
    }
    double dot = (d0 + d1) + (d2p + d3);
    double d2 = cvalid ? ((sq64[row] + sq64[(size_t)b * N_ + cand]) - 2.0 * dot)
                       : 1.0e300;
    const int candk = cvalid ? cand : (N_ + lane);   // unique tie-break keys
    int rank = 0;
    #pragma unroll 4
    for (int t = 0; t < KP_; ++t) {
        double od = __shfl(d2, t, 32);
        int    ok = __shfl(candk, t, 32);
        rank += (od < d2) || (od == d2 && ok < candk);
    }
    if (lane < KP_ && cvalid && rank < KNN_) {
        idx20[(size_t)row * KNN_ + rank] = cand;
        ii20[rl][rank] = cand;
    }
    __syncthreads();

    // BN stats + (max,min) per (row,o); pack f16x2 into u's slot (in place)
    const int o = tid & 63, w = tid >> 6;
    float s = 0.f, sq2 = 0.f;
    for (int rr = w; rr < 8; rr += 4) {
        const int row2 = rowBase + rr;
        const float uo = u[(size_t)row2 * 64 + o];
        float mx = -INFINITY, mn = INFINITY;
        #pragma unroll 4
        for (int k = 0; k < KNN_; ++k) {
            int j = ii20[rr][k];
            float y = uo + v[((size_t)b * N_ + j) * 64 + o];
            s += y;
            sq2 = fmaf(y, y, sq2);
            mx = fmaxf(mx, y);
            mn = fminf(mn, y);
        }
        ((unsigned*)u)[(size_t)row2 * 64 + o] = packf16(mx, mn);
    }
    red[tid] = s;
    red[256 + tid] = sq2;
    __syncthreads();
    if (tid < 64) {
        float t1 = red[o] + red[64 + o] + red[128 + o] + red[192 + o];
        float t2 = red[256 + o] + red[320 + o] + red[384 + o] + red[448 + o];
        psum[blockIdx.x * 64 + o] = t1;
        psq[blockIdx.x * 64 + o]  = t2;
    }
}

// ---------------------------------------------------------------------------
// Fallback rerank (gather from x) + separate stats (Layout B path)
// ---------------------------------------------------------------------------
__global__ __launch_bounds__(256) void k_rerank_fb(const float* __restrict__ x,
                                                   const double* __restrict__ sq64,
                                                   const int* __restrict__ idx24,
                                                   int* __restrict__ idx20) {
    __shared__ double dd[8 * KP_];
    __shared__ int    ii[8 * KP_];
    const int tid = threadIdx.x;
    const int rl = tid >> 5;
    const int lane = tid & 31;
    const int row = blockIdx.x * 8 + rl;
    const int b = row >> 12, n = row & (N_ - 1);
    const int craw = (lane < KP_) ? idx24[(size_t)row * KP_ + lane] : -1;
    const bool cvalid = craw >= 0;
    const int cand = cvalid ? (craw & (N_ - 1)) : 0;
    const float* __restrict__ xb = x + (size_t)b * C_ * N_;
    double dot = 0.0;
    #pragma unroll 4
    for (int c = 0; c < C_; ++c) {
        double xn = (double)xb[(size_t)c * N_ + n];
        double xj = (double)xb[(size_t)c * N_ + cand];
        dot = fma(xn, xj, dot);
    }
    double d2 = cvalid ? ((sq64[row] + sq64[b * N_ + cand]) - 2.0 * dot) : 1.0e300;
    const int candk = cvalid ? cand : (N_ + lane);
    if (lane < KP_) { dd[rl * KP_ + lane] = d2; ii[rl * KP_ + lane] = candk; }
    __syncthreads();
    if (lane < KP_ && cvalid) {
        int rank = 0;
        for (int t = 0; t < KP_; ++t) {
            double od = dd[rl * KP_ + t];
            int oi = ii[rl * KP_ + t];
            if (od < d2 || (od == d2 && oi < candk)) ++rank;
        }
        if (rank < KNN_) idx20[(size_t)row * KNN_ + rank] = cand;
    }
}

__global__ __launch_bounds__(256) void k_stats(const float* __restrict__ u,
                                               const float* __restrict__ v,
                                               const int* __restrict__ idx20,
                                               float* __restrict__ psum,
                                               float* __restrict__ psq) {
    __shared__ float red[512];
    const int tid = threadIdx.x;
    const int o = tid & 63, w = tid >> 6;
    const int base = blockIdx.x * 32;
    const int b = base >> 12;
    float s = 0.f, s2 = 0.f;
    for (int nn = w; nn < 32; nn += 4) {
        const int row = base + nn;
        const float uo = u[(size_t)row * 64 + o];
        const int* ip = idx20 + (size_t)row * KNN_;
        #pragma unroll 4
        for (int k = 0; k < KNN_; ++k) {
            int j = ip[k];
            float y = uo + v[((size_t)b * N_ + j) * 64 + o];
            s += y;
            s2 = fmaf(y, y, s2);
        }
    }
    red[tid] = s;
    red[256 + tid] = s2;
    __syncthreads();
    if (tid < 64) {
        float t  = red[o] + red[64 + o] + red[128 + o] + red[192 + o];
        float t2 = red[256 + o] + red[320 + o] + red[384 + o] + red[448 + o];
        psum[blockIdx.x * 64 + o] = t;
        psq[blockIdx.x * 64 + o]  = t2;
    }
}

// ---------------------------------------------------------------------------
// Kernel 4a: stage-1 reduction of psum/psq
// ---------------------------------------------------------------------------
__global__ __launch_bounds__(256) void k_bn1(const float* __restrict__ psum,
                                             const float* __restrict__ psq,
                                             float* __restrict__ psum2,
                                             float* __restrict__ psq2, int ppb) {
    __shared__ float red[512];
    const int tid = threadIdx.x;
    const int o = tid & 63, w = tid >> 6;
    const int base = blockIdx.x * ppb;
    float s = 0.f, s2 = 0.f;
    for (int p = w; p < ppb; p += 4) {
        s  += psum[(size_t)(base + p) * 64 + o];
        s2 += psq[(size_t)(base + p) * 64 + o];
    }
    red[tid] = s;
    red[256 + tid] = s2;
    __syncthreads();
    if (tid < 64) {
        psum2[blockIdx.x * 64 + o] = red[o] + red[64 + o] + red[128 + o] + red[192 + o];
        psq2[blockIdx.x * 64 + o]  = red[256 + o] + red[320 + o] + red[384 + o] + red[448 + o];
    }
}

// Kernel 4b: finalize BN -> per-channel scale/shift (fallback path only)
__global__ __launch_bounds__(1024) void k_bn(const float* __restrict__ psum,
                                             const float* __restrict__ psq,
                                             const float* __restrict__ gamma,
                                             const float* __restrict__ beta,
                                             float* __restrict__ scsh, int nparts) {
    __shared__ float red[2048];
    const int tid = threadIdx.x;
    const int o = tid & 63, part = tid >> 6;   // 16 parts
    float s = 0.f, s2 = 0.f;
    for (int i = part; i < nparts; i += 16) {
        s += psum[i * 64 + o];
        s2 += psq[i * 64 + o];
    }
    red[tid] = s;
    red[1024 + tid] = s2;
    __syncthreads();
    if (tid < 64) {
        float t = 0.f, t2 = 0.f;
        #pragma unroll
        for (int p = 0; p < 16; ++p) { t += red[p * 64 + o]; t2 += red[1024 + p * 64 + o]; }
        const float n = (float)B_ * (float)N_ * (float)KNN_;
        float mean = t / n;
        float var = t2 / n - mean * mean;
        float scale = gamma[o] / sqrtf(var + 1e-5f);
        scsh[o] = scale;
        scsh[64 + o] = beta[o] - mean * scale;
    }
}

// ---------------------------------------------------------------------------
// Kernel 5 (fast): BN finalize inlined + stream packed f16 (mx,mn) from u.
// ---------------------------------------------------------------------------
__global__ __launch_bounds__(256) void k_final(const float* __restrict__ u,
                                               const float* __restrict__ psum2,
                                               const float* __restrict__ psq2,
                                               const float* __restrict__ gamma,
                                               const float* __restrict__ beta,
                                               float* __restrict__ out) {
    __shared__ float tr[64 * 65];
    const int tid = threadIdx.x;
    const int o = tid & 63, w = tid >> 6;
    const int base = blockIdx.x * 64;
    const int b = base >> 12;
    const int nbase = base & (N_ - 1);

    // inline BN finalize (16 KB L2-hot reads, fixed summation order)
    float s = 0.f, s2 = 0.f;
    #pragma unroll 8
    for (int p = 0; p < 64; ++p) {
        s  += psum2[p * 64 + o];
        s2 += psq2[p * 64 + o];
    }
    const float ncnt = (float)B_ * (float)N_ * (float)KNN_;
    const float mean = s / ncnt;
    const float var  = s2 / ncnt - mean * mean;
    const float sc = gamma[o] / sqrtf(var + 1e-5f);
    const float sh = beta[o] - mean * sc;

    const unsigned* mm = (const unsigned*)u;
    for (int nn = w; nn < 64; nn += 4) {
        const int row = base + nn;
        unsigned pk = mm[(size_t)row * 64 + o];
        __half hx = *(__half*)&pk;
        unsigned short hiw = (unsigned short)(pk >> 16);
        __half hn = *(__half*)&hiw;
        float best = (sc >= 0.f) ? __half2float(hx) : __half2float(hn);
        float z = fmaf(best, sc, sh);
        tr[o * 65 + nn] = (z >= 0.f) ? z : 0.2f * z;
    }
    __syncthreads();
    for (int k = 0; k < 16; ++k) {
        int i = tid + k * 256;
        int o2 = i >> 6, n2 = i & 63;
        out[((size_t)b * 64 + o2) * N_ + nbase + n2] = tr[o2 * 65 + n2];
    }
}

// Kernel 5 (fallback): gather version (Layout B)
__global__ __launch_bounds__(256) void k_final_fb(const float* __restrict__ u,
                                                  const float* __restrict__ v,
                                                  const int* __restrict__ idx20,
                                                  const float* __restrict__ scsh,
                                                  float* __restrict__ out) {
    __shared__ float tr[64 * 65];
    const int tid = threadIdx.x;
    const int o = tid & 63, w = tid >> 6;
    const int base = blockIdx.x * 64;
    const int b = base >> 12;
    const int nbase = base & (N_ - 1);
    const float sc = scsh[o];
    const float sh = scsh[64 + o];
    for (int nn = w; nn < 64; nn += 4) {
        const int row = base + nn;
        const float uo = u[(size_t)row * 64 + o];
        const int* ip = idx20 + (size_t)row * KNN_;
        float mx = -INFINITY, mn = INFINITY;
        #pragma unroll 4
        for (int k = 0; k < KNN_; ++k) {
            int j = ip[k];
            float y = uo + v[((size_t)b * N_ + j) * 64 + o];
            mx = fmaxf(mx, y);
            mn = fminf(mn, y);
        }
        float best = (sc >= 0.f) ? mx : mn;
        float z = fmaf(best, sc, sh);
        tr[o * 65 + nn] = (z >= 0.f) ? z : 0.2f * z;
    }
    __syncthreads();
    for (int k = 0; k < 16; ++k) {
        int i = tid + k * 256;
        int o2 = i >> 6, n2 = i & 63;
        out[((size_t)b * 64 + o2) * N_ + nbase + n2] = tr[o2 * 65 + n2];
    }
}

// ---------------------------------------------------------------------------
extern "C" void kernel_launch(void* const* d_in, const int* in_sizes, int n_in,
                              void* d_out, int out_size, void* d_ws, size_t ws_size,
                              hipStream_t stream) {
    const float* x     = (const float*)d_in[0];
    const float* W     = (const float*)d_in[1];
    const float* bias  = (const float*)d_in[2];
    const float* gamma = (const float*)d_in[3];
    const float* beta  = (const float*)d_in[4];
    float* out = (float*)d_out;

    char* ws = (char*)d_ws;
    const size_t NEED_A = 38179328;    // layout A incl. xT + psum2/psq2
    const bool useA = (ws_size >= NEED_A);

    float *u, *v, *xT = nullptr, *sq32, *psum, *psq, *psum2, *psq2, *scsh;
    float2* sqp;
    double* sq64;
    int *idx24, *idx20;
    uint4* xh;
    int nparts;
    if (useA) {
        u     = (float*)(ws + 0);
        v     = (float*)(ws + 8388608);
        xT    = (float*)(ws + 16777216);
        xh    = (uint4*)(ws + 25165824);
        idx24 = (int*)(ws + 29360128);
        idx20 = (int*)(ws + 33030144);
        sq32  = (float*)(ws + 35651584);
        sq64  = (double*)(ws + 35782656);
        sqp   = (float2*)(ws + 36044800);
        psum  = (float*)(ws + 36048896);
        psq   = (float*)(ws + 37097472);
        scsh  = (float*)(ws + 38146048);
        psum2 = (float*)(ws + 38146560);
        psq2  = (float*)(ws + 38162944);
        nparts = 4096;
    } else {
        u     = (float*)(ws + 0);
        v     = (float*)(ws + 8388608);
        sq32  = (float*)(ws + 16777216);
        sq64  = (double*)(ws + 16908288);
        sqp   = (float2*)(ws + 17170432);
        psum  = (float*)(ws + 17174528);
        psq   = (float*)(ws + 17436672);
        scsh  = (float*)(ws + 17698816);
        idx24 = (int*)(ws + 17699328);
        xh    = (uint4*)(ws + 21369344);
        idx20 = (int*)(ws + 25563648);
        psum2 = (float*)(ws + 28185088);
        psq2  = (float*)(ws + 28201472);
        nparts = 1024;
    }

    hipLaunchKernelGGL(k_prep, dim3(512), dim3(256), 0, stream,
                       x, W, bias, u, v, sq32, sq64, xh, xT, sqp);
    hipLaunchKernelGGL(k_knn, dim3(1024), dim3(512), 39680, stream, xh, sq32, sqp, idx24);
    if (useA) {
        hipLaunchKernelGGL(k_rrs, dim3(4096), dim3(256), 0, stream,
                           xT, sq64, idx24, idx20, u, v, psum, psq);
        hipLaunchKernelGGL(k_bn1, dim3(64), dim3(256), 0, stream, psum, psq, psum2, psq2, nparts / 64);
        hipLaunchKernelGGL(k_final, dim3(512), dim3(256), 0, stream,
                           u, psum2, psq2, gamma, beta, out);
    } else {
        hipLaunchKernelGGL(k_rerank_fb, dim3(4096), dim3(256), 0, stream, x, sq64, idx24, idx20);
        hipLaunchKernelGGL(k_stats, dim3(1024), dim3(256), 0, stream, u, v, idx20, psum, psq);
        hipLaunchKernelGGL(k_bn1, dim3(64), dim3(256), 0, stream, psum, psq, psum2, psq2, nparts / 64);
        hipLaunchKernelGGL(k_bn, dim3(1), dim3(1024), 0, stream, psum2, psq2, gamma, beta, scsh, 64);
        hipLaunchKernelGGL(k_final_fb, dim3(512), dim3(256), 0, stream, u, v, idx20, scsh, out);
    }
}

// Round 17
// 137.288 us; speedup vs baseline: 1.0844x; 1.0844x over previous
//
#include <hip/hip_runtime.h>
#include <hip/hip_fp16.h>
#include <math.h>

#define B_    8
#define C_    64
#define N_    4096
#define OUT_  64
#define KNN_  20
#define KP_   28     // candidates kept per row for f64 rerank (slack for bf16 Gram + u16 quant)

// single-pass selection params
#define CAPL_ 176            // per-query main list capacity (lambda ~77, >10 sigma)
#define LSTR_ 177            // list stride (bank-stagger)
#define CAP2_ 64             // compacted list capacity (~36 expected)
#define L2S_  65             // list2/bhist stride (bank-stagger)
#define QSCK_ 546.13333f     // 65536 / 120  (score range [-80, 40) -> u16)
#define KQ_   (-2.0f * QSCK_)
#define KC_   (80.0f * QSCK_)

typedef __attribute__((ext_vector_type(8)))  short bf16x8;
typedef __attribute__((ext_vector_type(16))) float f32x16;

__device__ __forceinline__ unsigned short bf16rtn(float f) {
    unsigned u = __float_as_uint(f);
    u += 0x7FFFu + ((u >> 16) & 1u);
    return (unsigned short)(u >> 16);
}

__device__ __forceinline__ unsigned packf16(float a, float b) {
    __half ha = __float2half(a), hb = __float2half(b);
    unsigned short ua = *(unsigned short*)&ha, ub = *(unsigned short*)&hb;
    return (unsigned)ua | ((unsigned)ub << 16);
}

// ---------------------------------------------------------------------------
// Kernel 1: fused prep. Per block: 64-point tile of one batch.
// ---------------------------------------------------------------------------
__global__ __launch_bounds__(256) void k_prep(const float* __restrict__ x,
                                              const float* __restrict__ W,
                                              const float* __restrict__ bias,
                                              float* __restrict__ u,
                                              float* __restrict__ v,
                                              float* __restrict__ sq32,
                                              double* __restrict__ sq64,
                                              uint4* __restrict__ xh,
                                              float* __restrict__ xT,
                                              float2* __restrict__ sqp) {
    __shared__ float xs[64][65];     // [c][n]
    __shared__ float Wd[64 * 64];    // [c][o] = W1 - W2
    __shared__ float W2s[64 * 64];   // [c][o] = W2
    const int tid = threadIdx.x;
    const int b = blockIdx.x >> 6, nb = (blockIdx.x & 63) << 6;

    for (int k = 0; k < 16; ++k) {
        int i = tid + k * 256;
        int o = i & 63, c = i >> 6;
        float w1 = W[o * 128 + c];
        float w2 = W[o * 128 + 64 + c];
        Wd[c * 64 + o]  = w1 - w2;
        W2s[c * 64 + o] = w2;
    }
    for (int k = 0; k < 16; ++k) {
        int i = tid + k * 256;
        int c = i >> 6, n = i & 63;
        xs[c][n] = x[((size_t)b * 64 + c) * N_ + nb + n];
    }
    __syncthreads();

    const int o = tid & 63, w = tid >> 6;
    float uacc[16], vacc[16];
    #pragma unroll
    for (int i = 0; i < 16; ++i) { uacc[i] = 0.f; vacc[i] = 0.f; }
    for (int c = 0; c < 64; ++c) {
        float wd = Wd[c * 64 + o], w2 = W2s[c * 64 + o];
        #pragma unroll
        for (int i = 0; i < 16; ++i) {
            float xc = xs[c][w * 16 + i];
            uacc[i] = fmaf(wd, xc, uacc[i]);
            vacc[i] = fmaf(w2, xc, vacc[i]);
        }
    }
    const float bo = bias[o];
    #pragma unroll
    for (int i = 0; i < 16; ++i) {
        size_t row = (size_t)b * N_ + nb + w * 16 + i;
        u[row * 64 + o] = uacc[i] + bo;
        v[row * 64 + o] = vacc[i];
    }

    {   // pack xh (hi bf16 only)
        const int nl = tid & 63;
        #pragma unroll
        for (int gg = 0; gg < 2; ++gg) {
            const int g = (tid >> 6) + gg * 4;
            unsigned hw[4];
            #pragma unroll
            for (int e = 0; e < 4; ++e) {
                float x0 = xs[g * 8 + 2 * e][nl];
                float x1 = xs[g * 8 + 2 * e + 1][nl];
                hw[e] = (unsigned)bf16rtn(x0) | ((unsigned)bf16rtn(x1) << 16);
            }
            xh[(size_t)(b * 8 + g) * N_ + nb + nl] = make_uint4(hw[0], hw[1], hw[2], hw[3]);
        }
    }

    if (xT) {
        for (int k = 0; k < 16; ++k) {
            int i = tid + k * 256;
            int n = i >> 6, c = i & 63;
            xT[((size_t)b * N_ + nb + n) * 64 + c] = xs[c][n];
        }
    }

    // squared norms (f64 exact) + per-block stats partial (wave 0 only)
    if (tid < 64) {
        const int n = tid;
        double sq = 0.0;
        for (int c = 0; c < 64; ++c) {
            double xd = (double)xs[c][n];
            sq = fma(xd, xd, sq);
        }
        sq64[(size_t)b * N_ + nb + n] = sq;
        float fs = (float)sq;
        sq32[(size_t)b * N_ + nb + n] = fs;
        float s1 = fs, s2 = fs * fs;
        #pragma unroll
        for (int d = 1; d < 64; d <<= 1) {
            s1 += __shfl_xor(s1, d);
            s2 += __shfl_xor(s2, d);
        }
        if (tid == 0) sqp[blockIdx.x] = make_float2(s1, s2);
    }
}

// ---------------------------------------------------------------------------
// Kernel 2: SINGLE-PASS MFMA Gram + analytic-gate selection.
// 32 queries/block x 1024 blocks, 8 waves; XCD swizzle batch = blockIdx & 7.
// Tightened gate (z=-2.12, lambda~77); short rows padded with -1 sentinels.
// ---------------------------------------------------------------------------
__global__ __launch_bounds__(512, 8) void k_knn(const uint4* __restrict__ xh,
                                                const float* __restrict__ sq32,
                                                const float2* __restrict__ sqp,
                                                int* __restrict__ idx24) {
    extern __shared__ char smem[];
    unsigned* list  = (unsigned*)smem;                  // 32*177*4 = 22656
    unsigned* bhist = (unsigned*)(smem + 22656);        // 32*65*4  = 8320
    unsigned* list2 = (unsigned*)(smem + 30976);        // 32*65*4  = 8320
    unsigned* cnt   = (unsigned*)(smem + 39296);        // 128
    unsigned* cnt2  = (unsigned*)(smem + 39424);        // 128
    unsigned* edge  = (unsigned*)(smem + 39552);        // 128  -> total 39680

    const int tid = threadIdx.x;
    const int b   = blockIdx.x & 7;                 // XCD-affinity swizzle
    const int qb  = (blockIdx.x >> 3) << 5;         // q-group of 32
    const int wid = tid >> 6, l = tid & 63, h = l >> 5, ql = l & 31;
    const int jq  = wid * 512;
    const uint4* xhb = xh + (size_t)b * 8 * N_;
    const float* sqb = sq32 + b * N_;

    for (int i = tid; i < 32 * L2S_; i += 512) bhist[i] = 0u;
    if (tid < 32) { cnt[tid] = 0u; cnt2[tid] = 0u; }

    // batch stats from 64 k_prep partials (redundant per-wave reduce)
    float2 pp = sqp[b * 64 + l];
    float s1 = pp.x, s2 = pp.y;
    #pragma unroll
    for (int d = 1; d < 64; d <<= 1) { s1 += __shfl_xor(s1, d); s2 += __shfl_xor(s2, d); }
    const float mean = s1 * (1.0f / 4096.f);
    const float var  = s2 * (1.0f / 4096.f) - mean * mean;

    // per-lane gate: tightened z (lambda ~77; P(true-20 miss) ~4e-11/query)
    const float sqi = sqb[qb + ql];
    const float gg = -0.5f * (mean + 0.75f - 2.12f * sqrtf(var + 4.f * sqi));

    // B fragments (queries), persistent in regs
    bf16x8 Bh[4];
    #pragma unroll
    for (int kk = 0; kk < 4; ++kk)
        Bh[kk] = *(const bf16x8*)&xhb[(size_t)(2 * kk + h) * N_ + qb + ql];
    __syncthreads();   // lists/counts zeroed

    const int qq = ql;
    #pragma unroll 1
    for (int t = 0; t < 16; ++t) {
        const int jb = jq + t * 32;
        bf16x8 Ah[4];
        #pragma unroll
        for (int kk = 0; kk < 4; ++kk)
            Ah[kk] = *(const bf16x8*)&xhb[(size_t)(2 * kk + h) * N_ + jb + ql];
        float4 q0 = *(const float4*)(sqb + jb + 4 * h);
        float4 q1 = *(const float4*)(sqb + jb + 8 + 4 * h);
        float4 q2 = *(const float4*)(sqb + jb + 16 + 4 * h);
        float4 q3 = *(const float4*)(sqb + jb + 24 + 4 * h);

        float sq16[16];
        sq16[0]=q0.x; sq16[1]=q0.y; sq16[2]=q0.z; sq16[3]=q0.w;
        sq16[4]=q1.x; sq16[5]=q1.y; sq16[6]=q1.z; sq16[7]=q1.w;
        sq16[8]=q2.x; sq16[9]=q2.y; sq16[10]=q2.z; sq16[11]=q2.w;
        sq16[12]=q3.x; sq16[13]=q3.y; sq16[14]=q3.z; sq16[15]=q3.w;

        // fold -0.5*sq_j into the accumulator init: final a = dot - 0.5 sq_j
        f32x16 a0;
        #pragma unroll
        for (int i = 0; i < 16; ++i) a0[i] = -0.5f * sq16[i];
        #pragma unroll
        for (int kk = 0; kk < 4; ++kk)
            a0 = __builtin_amdgcn_mfma_f32_32x32x16_bf16(Ah[kk], Bh[kk], a0, 0, 0, 0);

        const int jv0 = jb + 4 * h;
        #pragma unroll
        for (int r = 0; r < 16; ++r) {
            float av = a0[r];
            if (av > gg) {
                float qf = fmaf(av, KQ_, KC_);               // quantized score
                qf = fminf(fmaxf(qf, 0.0f), 65535.0f);       // v_med3_f32
                unsigned key = ((unsigned)(int)qf << 12) |
                               (unsigned)(jv0 + (r & 3) + 8 * (r >> 2));
                unsigned slot = atomicAdd(&cnt[qq], 1u);
                if (slot < CAPL_) list[qq * LSTR_ + slot] = key;
            }
        }
    }
    __syncthreads();                    // all appends done

    // clamp counts, then build the bucket histogram from the stored keys
    if (tid < 32) {
        unsigned cc = cnt[tid];
        cnt[tid] = cc > CAPL_ ? CAPL_ : cc;
    }
    __syncthreads();
    {
        const int qh = tid >> 4, ph = tid & 15;
        const int cnh = (int)cnt[qh];
        for (int e = ph; e < cnh; e += 16)
            atomicAdd(&bhist[qh * L2S_ + (list[qh * LSTR_ + e] >> 22)], 1u);
    }
    __syncthreads();                    // histogram complete

    if (tid < 32) {
        unsigned c = 0, E = 63;
        #pragma unroll 1
        for (int bin = 0; bin < 64; ++bin) {
            c += bhist[tid * L2S_ + bin];
            if (c >= KP_) { E = (unsigned)bin; break; }
        }
        edge[tid] = E;
    }
    __syncthreads();

    const int qq2 = tid >> 4, pt = tid & 15;
    {   // compact: keep bucket <= E (~36 expected)
        const unsigned E = edge[qq2];
        const int cn = (int)cnt[qq2];
        for (int e = pt; e < cn; e += 16) {
            unsigned key = list[qq2 * LSTR_ + e];
            if ((key >> 22) <= E) {
                unsigned s2i = atomicAdd(&cnt2[qq2], 1u);
                if (s2i < CAP2_) list2[qq2 * L2S_ + s2i] = key;
            }
        }
    }
    __syncthreads();
    {   // exact rank-select top-28 by u32 key; pad short rows with -1 sentinel
        int cn2 = (int)cnt2[qq2]; cn2 = cn2 > CAP2_ ? CAP2_ : cn2;
        const size_t row = (size_t)b * N_ + qb + qq2;
        for (int e = pt; e < cn2; e += 16) {
            unsigned key = list2[qq2 * L2S_ + e];
            int rk = 0;
            for (int o = 0; o < cn2; ++o) rk += (list2[qq2 * L2S_ + o] < key);
            if (rk < KP_) idx24[row * KP_ + rk] = (int)(key & 0xFFFu);
        }
        for (int e = cn2 + pt; e < KP_; e += 16)
            idx24[row * KP_ + e] = -1;
    }
}

// ---------------------------------------------------------------------------
// Kernel 3 (fast, fused): f64 re-rank (xT) + BN stats + packed (max,min)
// in place into u.  R14 body; sentinels handled with ONE f64 select:
// craw<0 -> d2 = 1e30+lane (distinct, ranks last; rank<KNN_ guard excludes).
// ---------------------------------------------------------------------------
__global__ __launch_bounds__(256) void k_rrs(const float* __restrict__ xT,
                                             const double* __restrict__ sq64,
                                             const int* __restrict__ idx24,
                                             int* __restrict__ idx20,
                                             float* u,
                                             const float* __restrict__ v,
                                             float* __restrict__ psum,
                                             float* __restrict__ psq) {
    __shared__ float qs[8][64];
    __shared__ int   ii20[8][KNN_];
    __shared__ float red[512];
    const int tid = threadIdx.x;
    const int rl = tid >> 5, lane = tid & 31;
    const int bb = blockIdx.x & 7;                  // XCD-affinity swizzle
    const int rowBase = bb * N_ + (blockIdx.x >> 3) * 8;
    #pragma unroll
    for (int i = 0; i < 2; ++i) {
        int idx = tid + i * 256;
        qs[idx >> 6][idx & 63] = xT[(size_t)(rowBase + (idx >> 6)) * 64 + (idx & 63)];
    }
    __syncthreads();
    const int row = rowBase + rl;
    const int b = bb;
    const int craw = (lane < KP_) ? idx24[(size_t)row * KP_ + lane] : -1;
    const int cand = craw & (N_ - 1);               // sentinel -> 4095 (harmless)
    const float* __restrict__ cp = xT + ((size_t)b * N_ + cand) * 64;
    double d0 = 0.0, d1 = 0.0, d2p = 0.0, d3 = 0.0;   // 4-way split chain
    #pragma unroll
    for (int c4 = 0; c4 < 16; ++c4) {
        float4 p4 = *(const float4*)(cp + c4 * 4);
        float4 q4 = *(const float4*)(&qs[rl][c4 * 4]);
        d0 = fma((double)q4.x, (double)p4.x, d0);
        d1 = fma((double)q4.y, (double)p4.y, d1);
        d2p = fma((double)q4.z, (double)p4.z, d2p);
        d3 = fma((double)q4.w, (double)p4.w, d3);
    }
    double dot = (d0 + d1) + (d2p + d3);
    double d2 = (sq64[row] + sq64[(size_t)b * N_ + cand]) - 2.0 * dot;
    if (craw < 0) d2 = 1.0e30 + (double)lane;       // rank last, pairwise distinct
    int rank = 0;
    #pragma unroll 4
    for (int t = 0; t < KP_; ++t) {
        double od = __shfl(d2, t, 32);
        int    oi = __shfl(cand, t, 32);
        rank += (od < d2) || (od == d2 && oi < cand);
    }
    if (lane < KP_ && rank < KNN_) {
        idx20[(size_t)row * KNN_ + rank] = cand;
        ii20[rl][rank] = cand;
    }
    __syncthreads();

    // BN stats + (max,min) per (row,o); pack f16x2 into u's slot (in place)
    const int o = tid & 63, w = tid >> 6;
    float s = 0.f, sq2 = 0.f;
    for (int rr = w; rr < 8; rr += 4) {
        const int row2 = rowBase + rr;
        const float uo = u[(size_t)row2 * 64 + o];
        float mx = -INFINITY, mn = INFINITY;
        #pragma unroll 4
        for (int k = 0; k < KNN_; ++k) {
            int j = ii20[rr][k];
            float y = uo + v[((size_t)b * N_ + j) * 64 + o];
            s += y;
            sq2 = fmaf(y, y, sq2);
            mx = fmaxf(mx, y);
            mn = fminf(mn, y);
        }
        ((unsigned*)u)[(size_t)row2 * 64 + o] = packf16(mx, mn);
    }
    red[tid] = s;
    red[256 + tid] = sq2;
    __syncthreads();
    if (tid < 64) {
        float t1 = red[o] + red[64 + o] + red[128 + o] + red[192 + o];
        float t2 = red[256 + o] + red[320 + o] + red[384 + o] + red[448 + o];
        psum[blockIdx.x * 64 + o] = t1;
        psq[blockIdx.x * 64 + o]  = t2;
    }
}

// ---------------------------------------------------------------------------
// Fallback rerank (gather from x) + separate stats (Layout B path)
// ---------------------------------------------------------------------------
__global__ __launch_bounds__(256) void k_rerank_fb(const float* __restrict__ x,
                                                   const double* __restrict__ sq64,
                                                   const int* __restrict__ idx24,
                                                   int* __restrict__ idx20) {
    __shared__ double dd[8 * KP_];
    __shared__ int    ii[8 * KP_];
    const int tid = threadIdx.x;
    const int rl = tid >> 5;
    const int lane = tid & 31;
    const int row = blockIdx.x * 8 + rl;
    const int b = row >> 12, n = row & (N_ - 1);
    const int craw = (lane < KP_) ? idx24[(size_t)row * KP_ + lane] : -1;
    const int cand = craw & (N_ - 1);
    const float* __restrict__ xb = x + (size_t)b * C_ * N_;
    double dot = 0.0;
    #pragma unroll 4
    for (int c = 0; c < C_; ++c) {
        double xn = (double)xb[(size_t)c * N_ + n];
        double xj = (double)xb[(size_t)c * N_ + cand];
        dot = fma(xn, xj, dot);
    }
    double d2 = (sq64[row] + sq64[b * N_ + cand]) - 2.0 * dot;
    if (craw < 0) d2 = 1.0e30 + (double)lane;
    if (lane < KP_) { dd[rl * KP_ + lane] = d2; ii[rl * KP_ + lane] = cand; }
    __syncthreads();
    if (lane < KP_) {
        int rank = 0;
        for (int t = 0; t < KP_; ++t) {
            double od = dd[rl * KP_ + t];
            int oi = ii[rl * KP_ + t];
            if (od < d2 || (od == d2 && oi < cand)) ++rank;
        }
        if (rank < KNN_) idx20[(size_t)row * KNN_ + rank] = cand;
    }
}

__global__ __launch_bounds__(256) void k_stats(const float* __restrict__ u,
                                               const float* __restrict__ v,
                                               const int* __restrict__ idx20,
                                               float* __restrict__ psum,
                                               float* __restrict__ psq) {
    __shared__ float red[512];
    const int tid = threadIdx.x;
    const int o = tid & 63, w = tid >> 6;
    const int base = blockIdx.x * 32;
    const int b = base >> 12;
    float s = 0.f, s2 = 0.f;
    for (int nn = w; nn < 32; nn += 4) {
        const int row = base + nn;
        const float uo = u[(size_t)row * 64 + o];
        const int* ip = idx20 + (size_t)row * KNN_;
        #pragma unroll 4
        for (int k = 0; k < KNN_; ++k) {
            int j = ip[k];
            float y = uo + v[((size_t)b * N_ + j) * 64 + o];
            s += y;
            s2 = fmaf(y, y, s2);
        }
    }
    red[tid] = s;
    red[256 + tid] = s2;
    __syncthreads();
    if (tid < 64) {
        float t  = red[o] + red[64 + o] + red[128 + o] + red[192 + o];
        float t2 = red[256 + o] + red[320 + o] + red[384 + o] + red[448 + o];
        psum[blockIdx.x * 64 + o] = t;
        psq[blockIdx.x * 64 + o]  = t2;
    }
}

// ---------------------------------------------------------------------------
// Kernel 4a: stage-1 reduction of psum/psq
// ---------------------------------------------------------------------------
__global__ __launch_bounds__(256) void k_bn1(const float* __restrict__ psum,
                                             const float* __restrict__ psq,
                                             float* __restrict__ psum2,
                                             float* __restrict__ psq2, int ppb) {
    __shared__ float red[512];
    const int tid = threadIdx.x;
    const int o = tid & 63, w = tid >> 6;
    const int base = blockIdx.x * ppb;
    float s = 0.f, s2 = 0.f;
    for (int p = w; p < ppb; p += 4) {
        s  += psum[(size_t)(base + p) * 64 + o];
        s2 += psq[(size_t)(base + p) * 64 + o];
    }
    red[tid] = s;
    red[256 + tid] = s2;
    __syncthreads();
    if (tid < 64) {
        psum2[blockIdx.x * 64 + o] = red[o] + red[64 + o] + red[128 + o] + red[192 + o];
        psq2[blockIdx.x * 64 + o]  = red[256 + o] + red[320 + o] + red[384 + o] + red[448 + o];
    }
}

// Kernel 4b: finalize BN -> per-channel scale/shift (fallback path only)
__global__ __launch_bounds__(1024) void k_bn(const float* __restrict__ psum,
                                             const float* __restrict__ psq,
                                             const float* __restrict__ gamma,
                                             const float* __restrict__ beta,
                                             float* __restrict__ scsh, int nparts) {
    __shared__ float red[2048];
    const int tid = threadIdx.x;
    const int o = tid & 63, part = tid >> 6;   // 16 parts
    float s = 0.f, s2 = 0.f;
    for (int i = part; i < nparts; i += 16) {
        s += psum[i * 64 + o];
        s2 += psq[i * 64 + o];
    }
    red[tid] = s;
    red[1024 + tid] = s2;
    __syncthreads();
    if (tid < 64) {
        float t = 0.f, t2 = 0.f;
        #pragma unroll
        for (int p = 0; p < 16; ++p) { t += red[p * 64 + o]; t2 += red[1024 + p * 64 + o]; }
        const float n = (float)B_ * (float)N_ * (float)KNN_;
        float mean = t / n;
        float var = t2 / n - mean * mean;
        float scale = gamma[o] / sqrtf(var + 1e-5f);
        scsh[o] = scale;
        scsh[64 + o] = beta[o] - mean * scale;
    }
}

// ---------------------------------------------------------------------------
// Kernel 5 (fast): BN finalize inlined + stream packed f16 (mx,mn) from u.
// ---------------------------------------------------------------------------
__global__ __launch_bounds__(256) void k_final(const float* __restrict__ u,
                                               const float* __restrict__ psum2,
                                               const float* __restrict__ psq2,
                                               const float* __restrict__ gamma,
                                               const float* __restrict__ beta,
                                               float* __restrict__ out) {
    __shared__ float tr[64 * 65];
    const int tid = threadIdx.x;
    const int o = tid & 63, w = tid >> 6;
    const int base = blockIdx.x * 64;
    const int b = base >> 12;
    const int nbase = base & (N_ - 1);

    // inline BN finalize (16 KB L2-hot reads, fixed summation order)
    float s = 0.f, s2 = 0.f;
    #pragma unroll 8
    for (int p = 0; p < 64; ++p) {
        s  += psum2[p * 64 + o];
        s2 += psq2[p * 64 + o];
    }
    const float ncnt = (float)B_ * (float)N_ * (float)KNN_;
    const float mean = s / ncnt;
    const float var  = s2 / ncnt - mean * mean;
    const float sc = gamma[o] / sqrtf(var + 1e-5f);
    const float sh = beta[o] - mean * sc;

    const unsigned* mm = (const unsigned*)u;
    for (int nn = w; nn < 64; nn += 4) {
        const int row = base + nn;
        unsigned pk = mm[(size_t)row * 64 + o];
        __half hx = *(__half*)&pk;
        unsigned short hiw = (unsigned short)(pk >> 16);
        __half hn = *(__half*)&hiw;
        float best = (sc >= 0.f) ? __half2float(hx) : __half2float(hn);
        float z = fmaf(best, sc, sh);
        tr[o * 65 + nn] = (z >= 0.f) ? z : 0.2f * z;
    }
    __syncthreads();
    for (int k = 0; k < 16; ++k) {
        int i = tid + k * 256;
        int o2 = i >> 6, n2 = i & 63;
        out[((size_t)b * 64 + o2) * N_ + nbase + n2] = tr[o2 * 65 + n2];
    }
}

// Kernel 5 (fallback): gather version (Layout B)
__global__ __launch_bounds__(256) void k_final_fb(const float* __restrict__ u,
                                                  const float* __restrict__ v,
                                                  const int* __restrict__ idx20,
                                                  const float* __restrict__ scsh,
                                                  float* __restrict__ out) {
    __shared__ float tr[64 * 65];
    const int tid = threadIdx.x;
    const int o = tid & 63, w = tid >> 6;
    const int base = blockIdx.x * 64;
    const int b = base >> 12;
    const int nbase = base & (N_ - 1);
    const float sc = scsh[o];
    const float sh = scsh[64 + o];
    for (int nn = w; nn < 64; nn += 4) {
        const int row = base + nn;
        const float uo = u[(size_t)row * 64 + o];
        const int* ip = idx20 + (size_t)row * KNN_;
        float mx = -INFINITY, mn = INFINITY;
        #pragma unroll 4
        for (int k = 0; k < KNN_; ++k) {
            int j = ip[k];
            float y = uo + v[((size_t)b * N_ + j) * 64 + o];
            mx = fmaxf(mx, y);
            mn = fminf(mn, y);
        }
        float best = (sc >= 0.f) ? mx : mn;
        float z = fmaf(best, sc, sh);
        tr[o * 65 + nn] = (z >= 0.f) ? z : 0.2f * z;
    }
    __syncthreads();
    for (int k = 0; k < 16; ++k) {
        int i = tid + k * 256;
        int o2 = i >> 6, n2 = i & 63;
        out[((size_t)b * 64 + o2) * N_ + nbase + n2] = tr[o2 * 65 + n2];
    }
}

// ---------------------------------------------------------------------------
extern "C" void kernel_launch(void* const* d_in, const int* in_sizes, int n_in,
                              void* d_out, int out_size, void* d_ws, size_t ws_size,
                              hipStream_t stream) {
    const float* x     = (const float*)d_in[0];
    const float* W     = (const float*)d_in[1];
    const float* bias  = (const float*)d_in[2];
    const float* gamma = (const float*)d_in[3];
    const float* beta  = (const float*)d_in[4];
    float* out = (float*)d_out;

    char* ws = (char*)d_ws;
    const size_t NEED_A = 38179328;    // layout A incl. xT + psum2/psq2
    const bool useA = (ws_size >= NEED_A);

    float *u, *v, *xT = nullptr, *sq32, *psum, *psq, *psum2, *psq2, *scsh;
    float2* sqp;
    double* sq64;
    int *idx24, *idx20;
    uint4* xh;
    int nparts;
    if (useA) {
        u     = (float*)(ws + 0);
        v     = (float*)(ws + 8388608);
        xT    = (float*)(ws + 16777216);
        xh    = (uint4*)(ws + 25165824);
        idx24 = (int*)(ws + 29360128);
        idx20 = (int*)(ws + 33030144);
        sq32  = (float*)(ws + 35651584);
        sq64  = (double*)(ws + 35782656);
        sqp   = (float2*)(ws + 36044800);
        psum  = (float*)(ws + 36048896);
        psq   = (float*)(ws + 37097472);
        scsh  = (float*)(ws + 38146048);
        psum2 = (float*)(ws + 38146560);
        psq2  = (float*)(ws + 38162944);
        nparts = 4096;
    } else {
        u     = (float*)(ws + 0);
        v     = (float*)(ws + 8388608);
        sq32  = (float*)(ws + 16777216);
        sq64  = (double*)(ws + 16908288);
        sqp   = (float2*)(ws + 17170432);
        psum  = (float*)(ws + 17174528);
        psq   = (float*)(ws + 17436672);
        scsh  = (float*)(ws + 17698816);
        idx24 = (int*)(ws + 17699328);
        xh    = (uint4*)(ws + 21369344);
        idx20 = (int*)(ws + 25563648);
        psum2 = (float*)(ws + 28185088);
        psq2  = (float*)(ws + 28201472);
        nparts = 1024;
    }

    hipLaunchKernelGGL(k_prep, dim3(512), dim3(256), 0, stream,
                       x, W, bias, u, v, sq32, sq64, xh, xT, sqp);
    hipLaunchKernelGGL(k_knn, dim3(1024), dim3(512), 39680, stream, xh, sq32, sqp, idx24);
    if (useA) {
        hipLaunchKernelGGL(k_rrs, dim3(4096), dim3(256), 0, stream,
                           xT, sq64, idx24, idx20, u, v, psum, psq);
        hipLaunchKernelGGL(k_bn1, dim3(64), dim3(256), 0, stream, psum, psq, psum2, psq2, nparts / 64);
        hipLaunchKernelGGL(k_final, dim3(512), dim3(256), 0, stream,
                           u, psum2, psq2, gamma, beta, out);
    } else {
        hipLaunchKernelGGL(k_rerank_fb, dim3(4096), dim3(256), 0, stream, x, sq64, idx24, idx20);
        hipLaunchKernelGGL(k_stats, dim3(1024), dim3(256), 0, stream, u, v, idx20, psum, psq);
        hipLaunchKernelGGL(k_bn1, dim3(64), dim3(256), 0, stream, psum, psq, psum2, psq2, nparts / 64);
        hipLaunchKernelGGL(k_bn, dim3(1), dim3(1024), 0, stream, psum2, psq2, gamma, beta, scsh, 64);
        hipLaunchKernelGGL(k_final_fb, dim3(512), dim3(256), 0, stream, u, v, idx20, scsh, out);
    }
}